// Round 6
// baseline (269.461 us; speedup 1.0000x reference)
//
#include <hip/hip_runtime.h>
#include <math.h>

// SoftMSM loss on MI355X — round 5.
// E-space linear DP (exact exp-space softmin3) + hard gate, skewed wavefront
// split across TWO waves per batch (2 SIMDs/problem — round 4 showed we are
// issue-bound on a single SIMD: 4.7% chip VALUBusy = ~75% on the one busy SIMD).
//
//   F[i,j] = e^{i+j}E:  F = diag*A + up*B + left*C
//   A = e^{2-m2}; B = (dx*(x-y)>0 ? ex2+Em : 1); C = (dy*(x-y)<0 ? edy2+Em : 1)
//   cost = 1022 - log F[511,511]
//
//   Block = 128 threads = 2 waves; col-block q = tid (4 cols each).
//   Lane q runs row r = s - q at step s. In-wave boundary via __shfl_up;
//   wave0-lane63 -> wave1-lane0 via LDS ring (value+scale) + seq publish,
//   consumer polls (producer structurally ahead; wave 0 never waits).
//   diag input = cached previous-step left input (saves the bLp shuffle);
//   per-lane scale 2^kacc, rebased to max(kacc, k_in, cK) each step (all
//   shifts <= 0 -> overflow-proof), single-frexp normalize per row.

#define TT 512
#define BATCH 64
#define G 4
#define C1F 1.2011224087864498f    // sqrt(log2 e)
#define C2F 2.8853900817779268f    // 2*log2 e
#define K2F 0.13533528323661270f   // e^-2
#define LN2F 0.69314718055994531f

#if __has_builtin(__builtin_amdgcn_exp2f)
#define EXP2F(x) __builtin_amdgcn_exp2f(x)
#else
#define EXP2F(x) __expf((x) * LN2F)
#endif

__global__ __launch_bounds__(128) void msm_kernel(const float* __restrict__ x,
                                                  const float* __restrict__ y,
                                                  float* __restrict__ ws) {
  const int b = blockIdx.x;
  const int tid = threadIdx.x;       // 0..127
  const int wave = tid >> 6;
  const int lane = tid & 63;
  const int q = tid;                 // column-block id, cols [4q, 4q+4)

  __shared__ float XC[TT], DXS[TT], EX2[TT], YS[TT];
  __shared__ unsigned ringV[TT];
  __shared__ int ringK[TT];
  __shared__ volatile int seq;

  // ---- stage raw inputs ----
  float4 xq = ((const float4*)(x + b * TT))[tid];
  float4 yq = ((const float4*)(y + b * TT))[tid];
  ((float4*)DXS)[tid] = xq;          // raw x parked in DXS
  ((float4*)YS)[tid] = yq;
  if (tid == 0) seq = 0;
  __syncthreads();
  const float xm1 = (tid > 0) ? DXS[4 * tid - 1] : 0.0f;
  const float ym1 = (tid > 0) ? YS[4 * tid - 1] : 0.0f;
  __syncthreads();                   // neighbor raws consumed; safe to overwrite
  {
    float rx[G] = {xq.x, xq.y, xq.z, xq.w};
    float prev = xm1;
#pragma unroll
    for (int k = 0; k < G; ++k) {
      float dx = rx[k] - prev;       // row 0's dx unused (up input is 0)
      prev = rx[k];
      XC[4 * tid + k] = rx[k] * C1F;
      DXS[4 * tid + k] = dx;
      EX2[4 * tid + k] = __expf(-dx * dx);
    }
  }
  float yc[G], dyS[G], edy2[G];
  {
    float ry[G] = {yq.x, yq.y, yq.z, yq.w};
    float prev = ym1;
#pragma unroll
    for (int k = 0; k < G; ++k) {
      float dy = ry[k] - prev;       // col 0's dy unused (left input is 0)
      prev = ry[k];
      yc[k] = ry[k] * C1F;
      dyS[k] = dy;
      edy2[k] = __expf(-dy * dy);
    }
  }
  __syncthreads();

  float Ep[G] = {0.0f, 0.0f, 0.0f, 0.0f};
  float bLcS = 0.0f;                 // shfl payload: Ep[3] post-normalize
  float cB = 0.0f;                   // cached left input -> next step's diag
  int cK = 0;                        // its scale
  int kacc = 0;                      // F_true = stored * 2^kacc

  const int STEPSW = TT + 63 + wave * 64;   // wave0: 575, wave1: 639

  // prefetch row 0 data
  float cxc = XC[0], cdx = DXS[0], cex = EX2[0];

  for (int s = 0; s < STEPSW; ++s) {
    const int r = s - q;
    float bc_raw = __shfl_up(bLcS, 1);
    int k_in = __shfl_up(kacc, 1);
    if (lane == 0) {
      bc_raw = 0.0f;
      k_in = kacc;
      if (wave == 1 && r >= 0 && r < TT) {
        int sv = seq;                          // consumer: poll publish counter
        while (sv <= r) { __builtin_amdgcn_s_sleep(8); sv = seq; }
        bc_raw = __uint_as_float(ringV[r]);
        k_in = ringK[r];
      }
    }
    // prefetch next row's data (clamped) — latency hidden under compute
    int rn = s + 1 - q;
    rn = rn < 0 ? 0 : (rn > TT - 1 ? TT - 1 : rn);
    const float nxc = XC[rn], ndx = DXS[rn], nex = EX2[rn];

    if (r >= 0 && r < TT) {
      if (r == 0) { kacc = k_in; cK = k_in; }  // entry: adopt incoming scale (cB==0)
      int knew = kacc > k_in ? kacc : k_in;
      knew = knew > cK ? knew : cK;
      const float mMe = ldexpf(1.0f, kacc - knew);  // all <= 1: overflow-proof
      const float mIn = ldexpf(1.0f, k_in - knew);
      const float mCp = ldexpf(1.0f, cK - knew);
      float left = bc_raw * mIn;
      float diag = cB * mCp;
      if (q == 0 && r == 0) diag = K2F;        // global seed F[-1,-1] = e^{-2}

      float up[G];
#pragma unroll
      for (int k = 0; k < G; ++k) up[k] = Ep[k] * mMe;

      // weights + precombine (independent of the serial chain)
      float pre[G], Cv[G];
#pragma unroll
      for (int k = 0; k < G; ++k) {
        float s1 = cxc - yc[k];                      // (x-y)*sqrt(log2e)
        float A = EXP2F(__fmaf_rn(s1, -s1, C2F));    // e^{2-m2}
        float Em = A * K2F;                          // e^{-m2}
        float B = (cdx * s1 > 0.0f) ? (cex + Em) : 1.0f;
        Cv[k] = (dyS[k] * s1 < 0.0f) ? (edy2[k] + Em) : 1.0f;
        float dk = (k == 0) ? diag : up[k - 1];
        pre[k] = __fmaf_rn(dk, A, up[k] * B);
      }
      // serial chain: 4 dependent FMAs
      float l = left;
#pragma unroll
      for (int k = 0; k < G; ++k) {
        l = __fmaf_rn(l, Cv[k], pre[k]);
        Ep[k] = l;
      }

      // normalize: max Ep -> [0.5, 1)
      float vmax = fmaxf(fmaxf(Ep[0], Ep[1]), fmaxf(Ep[2], Ep[3]));
      unsigned ue = (__float_as_uint(vmax) >> 23) & 0xFFu;
      int e = (ue == 0u) ? -126 : ((int)ue - 126);
      float sc = ldexpf(1.0f, -e);
#pragma unroll
      for (int k = 0; k < G; ++k) Ep[k] *= sc;
      kacc = knew + e;
      bLcS = Ep[G - 1];

      if (wave == 0 && lane == 63) {             // producer: publish row r
        ringV[r] = __float_as_uint(bLcS);
        ringK[r] = kacc;
        seq = r + 1;    // same-wave LDS FIFO ordering publishes V/K first
      }
    }
    cB = bc_raw;        // this step's left input = next step's diag input
    cK = k_in;
    cxc = nxc; cdx = ndx; cex = nex;
  }

  if (tid == 127) {
    ws[b] = 1022.0f - (__logf(bLcS) + (float)kacc * LN2F);
  }
}

__global__ __launch_bounds__(64) void reduce_kernel(const float* __restrict__ ws,
                                                    float* __restrict__ out) {
  float v = ws[threadIdx.x];
#pragma unroll
  for (int off = 32; off > 0; off >>= 1) v += __shfl_down(v, off);
  if (threadIdx.x == 0) out[0] = v * (1.0f / BATCH);
}

extern "C" void kernel_launch(void* const* d_in, const int* in_sizes, int n_in,
                              void* d_out, int out_size, void* d_ws, size_t ws_size,
                              hipStream_t stream) {
  const float* x = (const float*)d_in[0];
  const float* y = (const float*)d_in[1];
  float* ws = (float*)d_ws;
  float* out = (float*)d_out;
  msm_kernel<<<BATCH, 128, 0, stream>>>(x, y, ws);
  reduce_kernel<<<1, 64, 0, stream>>>(ws, out);
}

// Round 7
// 262.453 us; speedup vs baseline: 1.0267x; 1.0267x over previous
//
#include <hip/hip_runtime.h>
#include <math.h>

// SoftMSM loss on MI355X — round 6.
// Round-4 skeleton (4 rows/step, 191 steps, verified absmax 0.0) with the
// 4x8 cell tile computed in ANTI-DIAGONAL WAVEFRONT ORDER inside registers:
// cell (i,k) needs (i,k-1), (i-1,k), (i-1,k-1) — all from earlier wavefronts,
// so the 4 rows' serial FMA chains interleave and per-step latency ~= one
// chain of (G+R) FMAs instead of 4 chains of G. Round 3/4/5 data showed
// per-ROW latency ~600 cyc invariant (864 = 264+600; 2663 = 264+4*600;
// 838 with half the cells) -> exposed dependency latency, not issue, is the
// wall. Also __launch_bounds__(64, 1): stop the compiler from capping VGPRs
// for occupancy we can't use (1 wave/SIMD resident) — register starvation
// serializes independent chains.
//
// Recursion (c=1, gamma=1), F = e^{i+j} * exp(-cost):
//   F[i,j] = F[i-1,j-1]*A + F[i-1,j]*B + F[i,j-1]*C
//   A = e^{2-m2}; B = (dx*(x-y)>0 ? ex2+Em : 1); C = (dy*(x-y)<0 ? edy2+Em : 1)
//   cost = 1022 - log(F[511,511])

#define TT 512
#define BATCH 64
#define G 8
#define R 4
#define NP (TT / R)              // 128 row-quads
#define STEPS (NP + 63)          // 191

#define C1F 1.2011224087864498f  // sqrt(log2 e)
#define C2F 2.8853900817779268f  // 2*log2 e
#define K2F 0.13533528323661270f // e^-2
#define LN2F 0.69314718055994531f

#if __has_builtin(__builtin_amdgcn_exp2f)
#define EXP2F(x) __builtin_amdgcn_exp2f(x)
#else
#define EXP2F(x) __expf((x) * LN2F)
#endif

#define QIDX(p) ((p) + ((p) >> 3))   // pad: breaks p <-> p+8 bank aliasing

__global__ __launch_bounds__(64, 1) void msm_kernel(const float* __restrict__ x,
                                                    const float* __restrict__ y,
                                                    float* __restrict__ ws) {
  const int b = blockIdx.x;
  const int j = threadIdx.x;           // 0..63
  const int base = j * G;

  __shared__ float4 XC4[NP + (NP >> 3)];   // xc = x * C1, rows 4p..4p+3
  __shared__ float4 DX4[NP + (NP >> 3)];   // dx
  __shared__ float4 EX4[NP + (NP >> 3)];   // exp(-dx^2)

  // ---- setup: x-derived row data ----
  {
    const float4* xv = (const float4*)(x + b * TT);
    float4 a0 = xv[j * 2], a1 = xv[j * 2 + 1];
    float rx[G] = {a0.x, a0.y, a0.z, a0.w, a1.x, a1.y, a1.z, a1.w};
    float prev = (base > 0) ? x[b * TT + base - 1] : 0.0f;
    float cc[G], dd[G], ee[G];
#pragma unroll
    for (int k = 0; k < G; ++k) {
      float dx = rx[k] - prev;         // row 0's dx unused (up input is 0)
      prev = rx[k];
      cc[k] = rx[k] * C1F;
      dd[k] = dx;
      ee[k] = __expf(-dx * dx);
    }
    XC4[QIDX(j * 2)]     = make_float4(cc[0], cc[1], cc[2], cc[3]);
    XC4[QIDX(j * 2 + 1)] = make_float4(cc[4], cc[5], cc[6], cc[7]);
    DX4[QIDX(j * 2)]     = make_float4(dd[0], dd[1], dd[2], dd[3]);
    DX4[QIDX(j * 2 + 1)] = make_float4(dd[4], dd[5], dd[6], dd[7]);
    EX4[QIDX(j * 2)]     = make_float4(ee[0], ee[1], ee[2], ee[3]);
    EX4[QIDX(j * 2 + 1)] = make_float4(ee[4], ee[5], ee[6], ee[7]);
  }
  // ---- setup: y-derived column registers ----
  float yc[G], dyS[G], edy2[G];
  {
    const float4* yv = (const float4*)(y + b * TT);
    float4 a0 = yv[j * 2], a1 = yv[j * 2 + 1];
    float ry[G] = {a0.x, a0.y, a0.z, a0.w, a1.x, a1.y, a1.z, a1.w};
    float ym1 = (base > 0) ? y[b * TT + base - 1] : 0.0f;
#pragma unroll
    for (int k = 0; k < G; ++k) {
      yc[k] = ry[k] * C1F;
      float dy = ry[k] - ym1;          // col 0's dy unused (left input is 0)
      dyS[k] = dy;
      edy2[k] = __expf(-dy * dy);
      ym1 = ry[k];
    }
  }
  __syncthreads();

  float Ep[G];                         // F[a-1, base..base+7] (last done row)
#pragma unroll
  for (int k = 0; k < G; ++k) Ep[k] = 0.0f;
  // carried last-col values: dc0=lastcol(a-1), dc1..dc4=lastcol(a..a+3)
  float dc0 = 0.0f, dc1 = 0.0f, dc2 = 0.0f, dc3 = 0.0f, dc4 = 0.0f;
  int kacc = 0;                        // F_true = stored * 2^kacc

  // prefetch quad 0
  float4 nxc = XC4[QIDX(0)], ndx = DX4[QIDX(0)], nex = EX4[QIDX(0)];

  for (int t = 0; t < STEPS; ++t) {
    // boundary exchange (wave-lockstep, unconditional)
    float r0 = __shfl_up(dc0, 1);
    float r1 = __shfl_up(dc1, 1);
    float r2 = __shfl_up(dc2, 1);
    float r3 = __shfl_up(dc3, 1);
    float r4 = __shfl_up(dc4, 1);
    int k_in = __shfl_up(kacc, 1);
    const int p = t - j;               // my row-quad index
    if (j == 0) {
      r0 = (p == 0) ? K2F : 0.0f;      // virtual seed F[-1,-1]=e^{-2}
      r1 = r2 = r3 = r4 = 0.0f;
      k_in = kacc;
    }
    // rotate prefetched row data; prefetch next quad
    float4 cxc = nxc, cdx = ndx, cex = nex;
    {
      int pn = t + 1 - j;
      pn = (pn < 0) ? 0 : ((pn > NP - 1) ? NP - 1 : pn);
      int qi = QIDX(pn);
      nxc = XC4[qi]; ndx = DX4[qi]; nex = EX4[qi];
    }

    if (p >= 0 && p < NP) {
      if (p == 0) kacc = k_in;         // pipeline entry: adopt neighbor scale
      const int knew = (k_in > kacc) ? k_in : kacc;
      const float mMe = ldexpf(1.0f, kacc - knew);  // <= 1: no overflow
      const float mIn = ldexpf(1.0f, k_in - knew);  // <= 1
      kacc = knew;
      const float dvv[R + 1] = {r0 * mIn, r1 * mIn, r2 * mIn, r3 * mIn, r4 * mIn};
      const float d0c = dc4 * mMe;     // lastcol(a-1) for next step's send
      float up0[G];
#pragma unroll
      for (int k = 0; k < G; ++k) up0[k] = Ep[k] * mMe;

      const float xc_[R] = {cxc.x, cxc.y, cxc.z, cxc.w};
      const float dx_[R] = {cdx.x, cdx.y, cdx.z, cdx.w};
      const float ex_[R] = {cex.x, cex.y, cex.z, cex.w};

      // ---- 4x8 tile, anti-diagonal wavefront order: rows overlap ----
      float T[R][G];
#pragma unroll
      for (int wf = 0; wf < G + R - 1; ++wf) {
#pragma unroll
        for (int i = 0; i < R; ++i) {
          const int k = wf - i;
          if (k < 0 || k >= G) continue;
          float s1 = xc_[i] - yc[k];                   // (x-y)*sqrt(log2e)
          float A = EXP2F(__fmaf_rn(s1, -s1, C2F));    // e^{2-m2}
          float Em = A * K2F;                          // e^{-m2}
          float B = (dx_[i] * s1 > 0.0f) ? (ex_[i] + Em) : 1.0f;
          float Cw = (dyS[k] * s1 < 0.0f) ? (edy2[k] + Em) : 1.0f;
          float u = (i == 0) ? up0[k] : T[i - 1][k];
          float d = (i == 0) ? ((k == 0) ? dvv[0] : up0[k - 1])
                             : ((k == 0) ? dvv[i] : T[i - 1][k - 1]);
          float l = (k == 0) ? dvv[i + 1] : T[i][k - 1];
          T[i][k] = __fmaf_rn(l, Cw, __fmaf_rn(d, A, u * B));
        }
      }

      dc0 = d0c;
      dc1 = T[0][G - 1]; dc2 = T[1][G - 1]; dc3 = T[2][G - 1];

      // normalize: max over ALL carried state -> everything <= 1 afterwards
      float vmax = fmaxf(fmaxf(fmaxf(T[3][0], T[3][1]), fmaxf(T[3][2], T[3][3])),
                         fmaxf(fmaxf(T[3][4], T[3][5]), fmaxf(T[3][6], T[3][7])));
      vmax = fmaxf(vmax, fmaxf(fmaxf(dc0, dc1), fmaxf(dc2, dc3)));
      unsigned ue = (__float_as_uint(vmax) >> 23) & 0xFFu;
      int e = (int)ue - 126;                  // vmax>0 always in active lanes
      float sc = ldexpf(1.0f, -e);
#pragma unroll
      for (int k = 0; k < G; ++k) Ep[k] = T[3][k] * sc;
      dc0 *= sc; dc1 *= sc; dc2 *= sc; dc3 *= sc;
      dc4 = Ep[G - 1];
      kacc += e;
    }
  }

  if (j == 63) {
    // cost = 1022 - log(F_true)
    ws[b] = 1022.0f - (__logf(Ep[G - 1]) + (float)kacc * LN2F);
  }
}

__global__ __launch_bounds__(64) void reduce_kernel(const float* __restrict__ ws,
                                                    float* __restrict__ out) {
  float v = ws[threadIdx.x];
#pragma unroll
  for (int off = 32; off > 0; off >>= 1) v += __shfl_down(v, off);
  if (threadIdx.x == 0) out[0] = v * (1.0f / BATCH);
}

extern "C" void kernel_launch(void* const* d_in, const int* in_sizes, int n_in,
                              void* d_out, int out_size, void* d_ws, size_t ws_size,
                              hipStream_t stream) {
  const float* x = (const float*)d_in[0];
  const float* y = (const float*)d_in[1];
  float* ws = (float*)d_ws;
  float* out = (float*)d_out;
  msm_kernel<<<BATCH, 64, 0, stream>>>(x, y, ws);
  reduce_kernel<<<1, 64, 0, stream>>>(ws, out);
}

// Round 8
// 223.871 us; speedup vs baseline: 1.2036x; 1.1723x over previous
//
#include <hip/hip_runtime.h>
#include <math.h>

// SoftMSM loss on MI355X — round 7.
// E-space linear DP (exact exp-space softmin3, verified absmax 0.0 in R4/R6)
// on a 128-lane pipeline: TWO barrier-synced waves per problem (no polling —
// R5's consumer spin-loop sat 1 step behind the producer forever).
//   lane L (0..127) owns cols [4L, 4L+4); at step t it processes row-pair
//   p = t - L (rows 2p, 2p+1). In-wave boundary via __shfl_up; the wave0->
//   wave1 seam (L=63 -> L=64) goes through a parity double-buffered LDS slot:
//   written at end of step t-1 by tid63, read at top of step t by tid64,
//   one __syncthreads per step makes it visible. 383 steps total.
//
// Recursion (c=1, gamma=1), F = e^{i+j} * exp(-cost):
//   F[i,j] = F[i-1,j-1]*A + F[i-1,j]*B + F[i,j-1]*C
//   A = e^{2-m2}; B = (dx*(x-y)>0 ? ex2+Em : 1); C = (dy*(x-y)<0 ? edy2+Em : 1)
//   cost = 1022 - log(F[511,511])
// Per-lane scale 2^kacc, rebased to max(kacc, k_in) per step (shifts <= 0,
// overflow-proof), per-step normalize of all carried state into [0.5, 1).

#define TT 512
#define BATCH 64
#define G 4                      // cols per lane
#define R 2                      // rows per step
#define LANES 128
#define NP (TT / R)              // 256 row-pairs
#define STEPS (NP + LANES - 1)   // 383

#define C1F 1.2011224087864498f  // sqrt(log2 e)
#define C2F 2.8853900817779268f  // 2*log2 e
#define K2F 0.13533528323661270f // e^-2
#define LN2F 0.69314718055994531f

#if __has_builtin(__builtin_amdgcn_exp2f)
#define EXP2F(x) __builtin_amdgcn_exp2f(x)
#else
#define EXP2F(x) __expf((x) * LN2F)
#endif

__global__ __launch_bounds__(128, 1) void msm_kernel(const float* __restrict__ x,
                                                     const float* __restrict__ y,
                                                     float* __restrict__ ws) {
  const int b = blockIdx.x;
  const int tid = threadIdx.x;       // 0..127; lane L == tid

  __shared__ float2 XC2[NP];         // {xc(2p), xc(2p+1)},  xc = x * C1
  __shared__ float2 DX2[NP];         // {dx(2p), dx(2p+1)}
  __shared__ float2 EX2[NP];         // {exp(-dx^2) pair}
  __shared__ float4 slotV[2];        // seam values {r0, r1, r2, -}
  __shared__ int    slotK[2];        // seam scale

  // ---- setup ----
  {
    float4 xq = ((const float4*)(x + b * TT))[tid];
    float rx[G] = {xq.x, xq.y, xq.z, xq.w};
    float prev = (tid > 0) ? x[b * TT + 4 * tid - 1] : 0.0f;
    float cc[G], dd[G], ee[G];
#pragma unroll
    for (int k = 0; k < G; ++k) {
      float dx = rx[k] - prev;       // row 0's dx unused (up input is 0)
      prev = rx[k];
      cc[k] = rx[k] * C1F;
      dd[k] = dx;
      ee[k] = __expf(-dx * dx);
    }
    XC2[2 * tid]     = make_float2(cc[0], cc[1]);
    XC2[2 * tid + 1] = make_float2(cc[2], cc[3]);
    DX2[2 * tid]     = make_float2(dd[0], dd[1]);
    DX2[2 * tid + 1] = make_float2(dd[2], dd[3]);
    EX2[2 * tid]     = make_float2(ee[0], ee[1]);
    EX2[2 * tid + 1] = make_float2(ee[2], ee[3]);
  }
  float yc[G], dyS[G], edy2[G];
  {
    float4 yq = ((const float4*)(y + b * TT))[tid];
    float ry[G] = {yq.x, yq.y, yq.z, yq.w};
    float prev = (tid > 0) ? y[b * TT + 4 * tid - 1] : 0.0f;
#pragma unroll
    for (int k = 0; k < G; ++k) {
      float dy = ry[k] - prev;       // col 0's dy unused (left input is 0)
      prev = ry[k];
      yc[k] = ry[k] * C1F;
      dyS[k] = dy;
      edy2[k] = __expf(-dy * dy);
    }
  }
  if (tid < 2) {
    slotV[tid] = make_float4(0.0f, 0.0f, 0.0f, 0.0f);
    slotK[tid] = 0;
  }
  __syncthreads();

  float Ep[G] = {0.0f, 0.0f, 0.0f, 0.0f};   // F[2p-1, owned cols]
  float dc0 = 0.0f, dc1 = 0.0f, dc2 = 0.0f; // lastcol(2p-2? -> 2p-1, 2p, 2p+1) carries
  int kacc = 0;                             // F_true = stored * 2^kacc

  float2 nxc = XC2[0], ndx = DX2[0], nex = EX2[0];  // prefetch (valid for tid 0)

  for (int t = 0; t < STEPS; ++t) {
    // intra-wave boundary exchange (lane L-1 -> L), pre-barrier is fine
    float r0 = __shfl_up(dc0, 1);
    float r1 = __shfl_up(dc1, 1);
    float r2 = __shfl_up(dc2, 1);
    int k_in = __shfl_up(kacc, 1);
    __syncthreads();                       // publishes slot written at t-1
    const int p = t - tid;
    if (tid == 64) {                       // seam: wave0 lane63 -> wave1 lane0
      float4 s = slotV[(t + 1) & 1];       // (t-1)&1 == (t+1)&1
      r0 = s.x; r1 = s.y; r2 = s.z;
      k_in = slotK[(t + 1) & 1];
    }
    if (tid == 0) {
      r0 = (p == 0) ? K2F : 0.0f;          // virtual seed F[-1,-1] = e^{-2}
      r1 = 0.0f; r2 = 0.0f;
      k_in = kacc;
    }
    // rotate prefetched row-pair data; prefetch next
    const float2 cxc = nxc, cdx = ndx, cex = nex;
    {
      int pn = t + 1 - tid;
      pn = (pn < 0) ? 0 : ((pn > NP - 1) ? NP - 1 : pn);
      nxc = XC2[pn]; ndx = DX2[pn]; nex = EX2[pn];
    }

    if (p >= 0 && p < NP) {
      if (p == 0) kacc = k_in;             // pipeline entry: adopt incoming scale
      const int knew = (k_in > kacc) ? k_in : kacc;
      const float mMe = ldexpf(1.0f, kacc - knew);  // <= 1
      const float mIn = ldexpf(1.0f, k_in - knew);  // <= 1
      kacc = knew;
      const float dv0 = r0 * mIn, dv1 = r1 * mIn, dv2 = r2 * mIn;
      const float nd0 = dc2 * mMe;         // lastcol(2p-1) for next send
      float u0 = Ep[0] * mMe, u1 = Ep[1] * mMe, u2 = Ep[2] * mMe, u3 = Ep[3] * mMe;

      // one cell: out = l*Cw + d*A + u*B
#define CELL(xcv, dxv, exv, kk, u, d, l, out)                          \
      {                                                                \
        float s1 = (xcv) - yc[kk];                                     \
        float A = EXP2F(__fmaf_rn(s1, -s1, C2F));                      \
        float Em = A * K2F;                                            \
        float B = ((dxv) * s1 > 0.0f) ? ((exv) + Em) : 1.0f;           \
        float Cw = (dyS[kk] * s1 < 0.0f) ? (edy2[kk] + Em) : 1.0f;     \
        out = __fmaf_rn(l, Cw, __fmaf_rn(d, A, (u) * B));              \
      }

      float T00, T01, T02, T03, T10, T11, T12, T13;
      // row 2p
      CELL(cxc.x, cdx.x, cex.x, 0, u0, dv0, dv1, T00);
      CELL(cxc.x, cdx.x, cex.x, 1, u1, u0, T00, T01);
      CELL(cxc.x, cdx.x, cex.x, 2, u2, u1, T01, T02);
      CELL(cxc.x, cdx.x, cex.x, 3, u3, u2, T02, T03);
      // row 2p+1
      CELL(cxc.y, cdx.y, cex.y, 0, T00, dv1, dv2, T10);
      CELL(cxc.y, cdx.y, cex.y, 1, T01, T00, T10, T11);
      CELL(cxc.y, cdx.y, cex.y, 2, T02, T01, T11, T12);
      CELL(cxc.y, cdx.y, cex.y, 3, T03, T02, T12, T13);
#undef CELL

      dc0 = nd0; dc1 = T03;                // dc2 set after normalize
      // normalize carried state into [0.5, 1)
      float vmax = fmaxf(fmaxf(fmaxf(T10, T11), fmaxf(T12, T13)),
                         fmaxf(dc0, dc1));
      unsigned ue = (__float_as_uint(vmax) >> 23) & 0xFFu;
      int e = (int)ue - 126;
      float sc = ldexpf(1.0f, -e);
      Ep[0] = T10 * sc; Ep[1] = T11 * sc; Ep[2] = T12 * sc; Ep[3] = T13 * sc;
      dc0 *= sc; dc1 *= sc; dc2 = Ep[3];
      kacc += e;

      if (tid == 63) {                     // producer: publish seam for t+1
        slotV[t & 1] = make_float4(dc0, dc1, dc2, 0.0f);
        slotK[t & 1] = kacc;
      }
    }
  }

  if (tid == 127) {
    // cost = 1022 - log(F_true)
    ws[b] = 1022.0f - (__logf(Ep[G - 1]) + (float)kacc * LN2F);
  }
}

__global__ __launch_bounds__(64) void reduce_kernel(const float* __restrict__ ws,
                                                    float* __restrict__ out) {
  float v = ws[threadIdx.x];
#pragma unroll
  for (int off = 32; off > 0; off >>= 1) v += __shfl_down(v, off);
  if (threadIdx.x == 0) out[0] = v * (1.0f / BATCH);
}

extern "C" void kernel_launch(void* const* d_in, const int* in_sizes, int n_in,
                              void* d_out, int out_size, void* d_ws, size_t ws_size,
                              hipStream_t stream) {
  const float* x = (const float*)d_in[0];
  const float* y = (const float*)d_in[1];
  float* ws = (float*)d_ws;
  float* out = (float*)d_out;
  msm_kernel<<<BATCH, LANES, 0, stream>>>(x, y, ws);
  reduce_kernel<<<1, 64, 0, stream>>>(ws, out);
}